// Round 4
// baseline (295.928 us; speedup 1.0000x reference)
//
#include <hip/hip_runtime.h>
#include <math.h>

// ============================================================================
// CliffordFourierHead — Cl(3,0) CGENN block. Round 4: deep split-K so every
// GEMM runs >=2-4 blocks/CU (round-3 limiter: 1-2 waves/SIMD, exposed global
// latency). Fused repack+xcast. 11 dispatches.
// ============================================================================

typedef unsigned short u16;
typedef __attribute__((ext_vector_type(8))) short short8;
typedef __attribute__((ext_vector_type(4))) float f32x4;

#define RSQRT2F 0.70710678118654752440f

// ---- Clifford product tables (verified rounds 0-3) ----
__device__ constexpr int PP_I[64] = {
  0,0,0,0,0,0,0,0,  1,1,1,1,1,1,1,1,  2,2,2,2,2,2,2,2,  3,3,3,3,3,3,3,3,
  4,4,4,4,4,4,4,4,  5,5,5,5,5,5,5,5,  6,6,6,6,6,6,6,6,  7,7,7,7,7,7,7,7};
__device__ constexpr int PP_K[64] = {
  0,1,2,3,4,5,6,7,  0,1,2,3,4,5,6,7,  0,1,2,3,4,5,6,7,  0,1,2,3,4,5,6,7,
  0,1,2,3,4,5,6,7,  0,1,2,3,4,5,6,7,  0,1,2,3,4,5,6,7,  0,1,2,3,4,5,6,7};
__device__ constexpr int PP_C[64] = {
   0, 1, 2, 3, 4, 5, 6, 7,
   9, 8,15,16,13,14,21,20,
  10,15, 8,17,12,21,14,19,
  11,16,17, 8,21,12,13,18,
  29,24,23,35,22,34,33,28,
  30,25,35,23,34,22,32,27,
  31,35,25,24,33,32,22,26,
  43,42,41,40,39,38,37,36};
__device__ constexpr int PP_T[64] = {
   0, 1, 1, 1, 2, 2, 2, 3,
   5, 4, 7, 7, 6, 6, 9, 8,
   5, 7, 4, 7, 6, 9, 6, 8,
   5, 7, 7, 4, 9, 6, 6, 8,
  13,11,11,15,10,14,14,12,
  13,11,15,11,14,10,14,12,
  13,15,11,11,14,14,10,12,
  19,18,18,18,17,17,17,16};
__device__ constexpr int PP_J[64] = {
  0,1,2,3,4,5,6,7,
  1,0,4,5,2,3,7,6,
  2,4,0,6,1,7,3,5,
  3,5,6,0,7,1,2,4,
  4,2,1,7,0,6,5,3,
  5,3,7,1,6,0,4,2,
  6,7,3,2,5,4,0,1,
  7,6,5,4,3,2,1,0};
__device__ constexpr float PP_S[64] = {
  1, 1, 1, 1, 1, 1, 1, 1,
  1, 1, 1, 1, 1, 1, 1, 1,
  1,-1, 1, 1,-1,-1, 1,-1,
  1,-1,-1, 1, 1,-1,-1, 1,
  1,-1, 1, 1,-1,-1, 1,-1,
  1,-1,-1, 1, 1,-1,-1, 1,
  1, 1,-1, 1,-1, 1,-1,-1,
  1, 1,-1, 1,-1, 1,-1,-1};

__device__ constexpr int GJ_CNT[8] = {4,6,6,6,6,6,6,4};
__device__ constexpr int GJ_C[8][6] = {
  {0,8,22,36,0,0},
  {1,9,12,23,26,37},
  {2,10,13,24,27,38},
  {3,11,14,25,28,39},
  {4,15,18,29,32,40},
  {5,16,19,30,33,41},
  {6,17,20,31,34,42},
  {7,21,35,43,0,0}};
__device__ constexpr int GJ_T[8][6] = {
  {0,4,10,16,0,0},
  {1,5,6,11,12,17},
  {1,5,6,11,12,17},
  {1,5,6,11,12,17},
  {2,7,8,13,14,18},
  {2,7,8,13,14,18},
  {2,7,8,13,14,18},
  {3,9,15,19,0,0}};
__device__ constexpr int GRADE[8] = {0,1,1,1,2,2,2,3};

__device__ inline float sigm(float x) { return 1.0f / (1.0f + expf(-x)); }
__device__ inline u16 f2bf(float f) {
  unsigned u = __float_as_uint(f);
  return (u16)((u + 0x7fffu + ((u >> 16) & 1u)) >> 16);
}
__device__ inline float bf2f(u16 h) { return __uint_as_float(((unsigned)h) << 16); }

// ============================================================================
// bf16 MFMA GEMM, multi-pass + split-K over flattened (pass, k-chunk) list.
// blockIdx.z = (set, j, slice). Slices write disjoint fp32 partial planes
// [slice*8+j][planeO]; consumers sum slices. 128x128 tile, BK=64, 4 waves,
// 4x4 frags of 16x16x32 bf16 MFMA, XOR-swizzled LDS.
// ============================================================================
#define BT 128
#define MT 128
#define BKc 64

__global__ __launch_bounds__(256) void mfma_gemm(
    const u16* __restrict__ Alin, const u16* __restrict__ Pfeat,
    const u16* __restrict__ WLin, const u16* __restrict__ WLin2,
    const u16* __restrict__ WGp,
    float* __restrict__ out1, float* __restrict__ out2,
    int N, int M, int aug, int planeA, int planeO, int KSbits, int KCbits)
{
  const int zz    = blockIdx.z;
  const int set   = zz >> (3 + KSbits);
  const int rem   = zz & ((8 << KSbits) - 1);
  const int j     = rem >> KSbits;
  const int slice = rem & ((1 << KSbits) - 1);
  const u16* WL   = set ? WLin2 : WLin;
  float* outp     = set ? out2 : out1;

  const int b0   = blockIdx.y * BT;
  const int m0   = blockIdx.x * MT;
  const int tid  = threadIdx.x;
  const int lane = tid & 63;
  const int wave = tid >> 6;
  const int wr   = wave >> 1;
  const int wc   = wave & 1;
  const int l15  = lane & 15;
  const int lq   = lane >> 4;

  __shared__ u16 As[BT * BKc];
  __shared__ u16 Bs[MT * BKc];

  f32x4 zero = {0.f, 0.f, 0.f, 0.f};
  f32x4 acc[4][4];
  #pragma unroll
  for (int r = 0; r < 4; ++r)
    #pragma unroll
    for (int c = 0; c < 4; ++c) acc[r][c] = zero;

  const int g = GRADE[j];
  const int npass = aug ? (1 + GJ_CNT[j]) : 1;
  const int KC = 1 << KCbits;
  const int cper = (npass << KCbits) >> KSbits;   // even division by design
  const int cbeg = slice * cper;
  const int lrow = tid >> 3;
  const int lcg  = tid & 7;

  for (int ci = cbeg; ci < cbeg + cper; ++ci) {
    const int p  = ci >> KCbits;
    const int k0 = (ci & (KC - 1)) << 6;
    const u16* Abase = (p == 0) ? Alin + (size_t)j * planeA
                                : Pfeat + (size_t)GJ_C[j][p - 1] * planeA;
    const u16* Wbase = (p == 0) ? WL + (size_t)g * M * N
                                : WGp + (size_t)GJ_T[j][p - 1] * M * N;
    __syncthreads();
    #pragma unroll
    for (int q = 0; q < 4; ++q) {
      int row = lrow + q * 32;
      short8 va = *(const short8*)(Abase + (size_t)(b0 + row) * N + k0 + lcg * 8);
      *(short8*)(&As[row * BKc + (lcg ^ (row & 7)) * 8]) = va;
    }
    #pragma unroll
    for (int q = 0; q < 4; ++q) {
      int row = lrow + q * 32;
      short8 vb = *(const short8*)(Wbase + (size_t)(m0 + row) * N + k0 + lcg * 8);
      *(short8*)(&Bs[row * BKc + (lcg ^ (row & 7)) * 8]) = vb;
    }
    __syncthreads();
    #pragma unroll
    for (int s = 0; s < 2; ++s) {
      const int kq = s * 4 + lq;
      short8 af[4], bfr[4];
      #pragma unroll
      for (int r = 0; r < 4; ++r) {
        int row = wr * 64 + r * 16 + l15;
        af[r] = *(const short8*)(&As[row * BKc + (kq ^ (row & 7)) * 8]);
      }
      #pragma unroll
      for (int c = 0; c < 4; ++c) {
        int row = wc * 64 + c * 16 + l15;
        bfr[c] = *(const short8*)(&Bs[row * BKc + (kq ^ (row & 7)) * 8]);
      }
      #pragma unroll
      for (int r = 0; r < 4; ++r)
        #pragma unroll
        for (int c = 0; c < 4; ++c)
          acc[r][c] = __builtin_amdgcn_mfma_f32_16x16x32_bf16(af[r], bfr[c], acc[r][c], 0, 0, 0);
    }
  }

  float* obase = outp + (size_t)(slice * 8 + j) * planeO;
  #pragma unroll
  for (int r = 0; r < 4; ++r)
    #pragma unroll
    for (int c = 0; c < 4; ++c)
      #pragma unroll
      for (int e = 0; e < 4; ++e) {
        int bb = b0 + wr * 64 + r * 16 + lq * 4 + e;
        int mm = m0 + wc * 64 + c * 16 + l15;
        obase[(size_t)bb * M + mm] = acc[r][c][e];
      }
}

// ============================================================================
// Fused repack (8 weight tensors) + xcast (y==8): fp32 -> bf16 planes
// ============================================================================
struct RepackDesc { const float* in; u16* out; int MN; int S; };
struct RepackArgs { RepackDesc d[8]; const float* x; u16* xp; int PS; };

__global__ void repack_all(RepackArgs a)
{
  int mn = blockIdx.x * 256 + threadIdx.x;
  if (blockIdx.y == 8) {
    if (mn >= a.PS) return;
    float v[8];
    *(float4*)(v)     = *(const float4*)(a.x + (size_t)mn * 8);
    *(float4*)(v + 4) = *(const float4*)(a.x + (size_t)mn * 8 + 4);
    #pragma unroll
    for (int jj = 0; jj < 8; ++jj) a.xp[(size_t)jj * a.PS + mn] = f2bf(v[jj]);
    return;
  }
  RepackDesc d = a.d[blockIdx.y];
  if (mn >= d.MN) return;
  if (d.S == 4) {
    float4 v = ((const float4*)d.in)[mn];
    d.out[(size_t)0 * d.MN + mn] = f2bf(v.x);
    d.out[(size_t)1 * d.MN + mn] = f2bf(v.y);
    d.out[(size_t)2 * d.MN + mn] = f2bf(v.z);
    d.out[(size_t)3 * d.MN + mn] = f2bf(v.w);
  } else {  // S == 20
    #pragma unroll
    for (int q = 0; q < 5; ++q) {
      float4 v = *(const float4*)(d.in + (size_t)mn * 20 + q * 4);
      d.out[(size_t)(q * 4 + 0) * d.MN + mn] = f2bf(v.x);
      d.out[(size_t)(q * 4 + 1) * d.MN + mn] = f2bf(v.y);
      d.out[(size_t)(q * 4 + 2) * d.MN + mn] = f2bf(v.z);
      d.out[(size_t)(q * 4 + 3) * d.MN + mn] = f2bf(v.w);
    }
  }
}

// fused: v = sum_slices(vpart) -> CGENN norm(na) -> pair products with u -> P bf16
__global__ void pair_norm_p(const u16* __restrict__ up, const float* __restrict__ vpart,
                            const float* __restrict__ na, u16* __restrict__ Pp,
                            int PS, int M, int KS)
{
  int t = blockIdx.x * 256 + threadIdx.x;
  if (t >= PS) return;
  int m = t % M;
  float u[8], v[8];
  #pragma unroll
  for (int jj = 0; jj < 8; ++jj) {
    u[jj] = bf2f(up[(size_t)jj * PS + t]);
    float s = 0.f;
    for (int sl = 0; sl < KS; ++sl) s += vpart[(size_t)(sl * 8 + jj) * PS + t];
    v[jj] = s;
  }
  float q[4];
  q[0] = sqrtf(v[0] * v[0]);
  q[1] = sqrtf(v[1] * v[1] + v[2] * v[2] + v[3] * v[3]);
  q[2] = sqrtf(v[4] * v[4] + v[5] * v[5] + v[6] * v[6]);
  q[3] = sqrtf(v[7] * v[7]);
  float sc[4];
  #pragma unroll
  for (int gg = 0; gg < 4; ++gg) {
    float sa = sigm(na[m * 4 + gg]);
    sc[gg] = 1.0f / (sa * (q[gg] - 1.0f) + 1.0f + 1e-6f);
  }
  #pragma unroll
  for (int jj = 0; jj < 8; ++jj) v[jj] *= sc[GRADE[jj]];
  float p[44];
  #pragma unroll
  for (int c = 0; c < 44; ++c) p[c] = 0.f;
  #pragma unroll
  for (int e = 0; e < 64; ++e)
    p[PP_C[e]] += PP_S[e] * u[PP_I[e]] * v[PP_K[e]];
  #pragma unroll
  for (int c = 0; c < 44; ++c) Pp[(size_t)c * PS + t] = f2bf(p[c]);
}

// h = mv_silu((sum_slices + bias0)/sqrt2) -> bf16 planes
__global__ void bias_silu_p(const float* __restrict__ hpart, const float* __restrict__ bias,
                            const float* __restrict__ ga, const float* __restrict__ gb,
                            u16* __restrict__ sh, int PS, int M, int KS)
{
  int t = blockIdx.x * 256 + threadIdx.x;
  if (t >= PS) return;
  int m = t % M;
  float v[8];
  #pragma unroll
  for (int jj = 0; jj < 8; ++jj) {
    float s = 0.f;
    for (int sl = 0; sl < KS; ++sl) s += hpart[(size_t)(sl * 8 + jj) * PS + t];
    v[jj] = s;
  }
  v[0] += bias[m];
  #pragma unroll
  for (int jj = 0; jj < 8; ++jj) v[jj] *= RSQRT2F;
  float inv[4];
  inv[0] = v[0];
  inv[1] = v[1]*v[1] + v[2]*v[2] + v[3]*v[3];
  inv[2] = v[4]*v[4] + v[5]*v[5] + v[6]*v[6];
  inv[3] = v[7]*v[7];
  float gt[4];
  #pragma unroll
  for (int gg = 0; gg < 4; ++gg)
    gt[gg] = sigm(ga[m * 4 + gg] * inv[gg] + gb[m * 4 + gg]);
  #pragma unroll
  for (int jj = 0; jj < 8; ++jj)
    sh[(size_t)jj * PS + t] = f2bf(v[jj] * gt[GRADE[jj]]);
}

// h2 = mv_silu((sum llg + bias0 + cwGP(u, norm(sum hr); wg))/sqrt2) -> bf16 planes
__global__ void cw_silu_p(const float* __restrict__ llgp, const u16* __restrict__ up,
                          const float* __restrict__ hrp, const float* __restrict__ na,
                          const float* __restrict__ wg, const float* __restrict__ bias,
                          const float* __restrict__ ga, const float* __restrict__ gb,
                          u16* __restrict__ sh, int PS, int M, int KS)
{
  int t = blockIdx.x * 256 + threadIdx.x;
  if (t >= PS) return;
  int n = t % M;
  float acc[8], u[8], v[8], w[20];
  #pragma unroll
  for (int jj = 0; jj < 8; ++jj) {
    float sl_ = 0.f, sv = 0.f;
    for (int sl = 0; sl < KS; ++sl) {
      sl_ += llgp[(size_t)(sl * 8 + jj) * PS + t];
      sv  += hrp[(size_t)(sl * 8 + jj) * PS + t];
    }
    acc[jj] = sl_;
    v[jj]   = sv;
    u[jj]   = bf2f(up[(size_t)jj * PS + t]);
  }
  float q[4];
  q[0] = sqrtf(v[0] * v[0]);
  q[1] = sqrtf(v[1] * v[1] + v[2] * v[2] + v[3] * v[3]);
  q[2] = sqrtf(v[4] * v[4] + v[5] * v[5] + v[6] * v[6]);
  q[3] = sqrtf(v[7] * v[7]);
  float sc[4];
  #pragma unroll
  for (int gg = 0; gg < 4; ++gg) {
    float sa = sigm(na[n * 4 + gg]);
    sc[gg] = 1.0f / (sa * (q[gg] - 1.0f) + 1.0f + 1e-6f);
  }
  #pragma unroll
  for (int jj = 0; jj < 8; ++jj) v[jj] *= sc[GRADE[jj]];
  #pragma unroll
  for (int qq = 0; qq < 5; ++qq)
    *(float4*)(w + qq * 4) = *(const float4*)(wg + (size_t)n * 20 + qq * 4);
  acc[0] += bias[n];
  #pragma unroll
  for (int e = 0; e < 64; ++e)
    acc[PP_J[e]] += PP_S[e] * u[PP_I[e]] * v[PP_K[e]] * w[PP_T[e]];
  #pragma unroll
  for (int jj = 0; jj < 8; ++jj) acc[jj] *= RSQRT2F;
  float inv[4];
  inv[0] = acc[0];
  inv[1] = acc[1]*acc[1] + acc[2]*acc[2] + acc[3]*acc[3];
  inv[2] = acc[4]*acc[4] + acc[5]*acc[5] + acc[6]*acc[6];
  inv[3] = acc[7]*acc[7];
  float gt[4];
  #pragma unroll
  for (int gg = 0; gg < 4; ++gg)
    gt[gg] = sigm(ga[n * 4 + gg] * inv[gg] + gb[n * 4 + gg]);
  #pragma unroll
  for (int jj = 0; jj < 8; ++jj)
    sh[(size_t)jj * PS + t] = f2bf(acc[jj] * gt[GRADE[jj]]);
}

// out[b,m,j] = (sum_slices + bias0)/sqrt2, planar -> interleaved
__global__ void final_p(const float* __restrict__ pre, const float* __restrict__ bias,
                        float* __restrict__ outp, int PS, int M, int KS)
{
  int t = blockIdx.x * 256 + threadIdx.x;
  if (t >= PS) return;
  int m = t % M;
  float v[8];
  #pragma unroll
  for (int jj = 0; jj < 8; ++jj) {
    float s = 0.f;
    for (int sl = 0; sl < KS; ++sl) s += pre[(size_t)(sl * 8 + jj) * PS + t];
    v[jj] = s;
  }
  v[0] += bias[m];
  #pragma unroll
  for (int jj = 0; jj < 8; ++jj) v[jj] *= RSQRT2F;
  *(float4*)(outp + (size_t)t * 8)     = *(float4*)(v);
  *(float4*)(outp + (size_t)t * 8 + 4) = *(float4*)(v + 4);
}

// ============================================================================
extern "C" void kernel_launch(void* const* d_in, const int* in_sizes, int n_in,
                              void* d_out, int out_size, void* d_ws, size_t ws_size,
                              hipStream_t stream)
{
  const float* x     = (const float*)d_in[0];
  const float* lr1_w = (const float*)d_in[1];
  const float* n1_a  = (const float*)d_in[2];
  const float* ll1_w = (const float*)d_in[3];
  const float* ll1_b = (const float*)d_in[4];
  const float* w1    = (const float*)d_in[5];
  const float* act_a = (const float*)d_in[6];
  const float* act_b = (const float*)d_in[7];
  const float* lrg_w = (const float*)d_in[8];
  const float* ng_a  = (const float*)d_in[9];
  const float* llg_w = (const float*)d_in[10];
  const float* llg_b = (const float*)d_in[11];
  const float* wg    = (const float*)d_in[12];
  const float* lr2_w = (const float*)d_in[13];
  const float* n2_a  = (const float*)d_in[14];
  const float* ll2_w = (const float*)d_in[15];
  const float* ll2_b = (const float*)d_in[16];
  const float* w2    = (const float*)d_in[17];
  float* out = (float*)d_out;

  // ---- workspace carve-up (u16 75 MB, then two 67 MB fp32 arenas) ----
  u16* W = (u16*)d_ws;
  size_t o = 0;
  u16* WL1  = W + o; o +=  262144;   // [4][256*256]
  u16* WLL1 = W + o; o +=  524288;   // [4][512*256]
  u16* WG1  = W + o; o += 2621440;   // [20][512*256]
  u16* WLRG = W + o; o += 1048576;   // [4][512*512]
  u16* WLLG = W + o; o += 1048576;
  u16* WLR2 = W + o; o += 1048576;
  u16* WLL2 = W + o; o +=  262144;   // [4][128*512]
  u16* WG2  = W + o; o += 1310720;   // [20][128*512]
  u16* XB   = W + o; o += 2097152;   // [8][1024*256]
  u16* HB   = W + o; o += 4194304;   // [8][1024*512] (h1 bf16, then h2 bf16)
  u16* P    = W + o; o += 23068672;  // [44][1024*512]
  float* f1 = (float*)(W + o);       // 16,777,216 f: lr1 part(KS4,32MB) / ll1 part(KS4,64MB)
                                     //               / lr2 part(KS2,32MB) / outPre part(KS8,32MB)
  float* f2 = f1 + 16777216;         // 16,777,216 f: hr part(KS2,32MB) + llg part(KS2,32MB)
  float* hrP  = f2;
  float* llgP = f2 + 8388608;
  // total ws use: 74,973,184 + 134,217,728 = 209,190,912 B  (ws = 256 MiB)

  dim3 blk(256);
  const int PS1 = 1024 * 256, PS2 = 1024 * 512, PSO = 1024 * 128;

  // ---- fused repacks + xcast ----
  RepackArgs ra = {{
    {lr1_w, WL1, 65536, 4}, {ll1_w, WLL1, 131072, 4}, {w1, WG1, 131072, 20},
    {lrg_w, WLRG, 262144, 4}, {llg_w, WLLG, 262144, 4}, {lr2_w, WLR2, 262144, 4},
    {ll2_w, WLL2, 65536, 4}, {w2, WG2, 65536, 20}},
    x, XB, PS1};
  repack_all<<<dim3(1024, 9), blk, 0, stream>>>(ra);

  // ---- fcgp1 (N=256, M=512) ----
  // lr1: KS=4 (1 chunk/slice) -> 512 blocks
  mfma_gemm<<<dim3(2, 8, 32), blk, 0, stream>>>(XB, nullptr, WL1, nullptr, nullptr,
      f1, nullptr, 256, 256, 0, PS1, PS1, 2, 2);
  pair_norm_p<<<PS1 / 256, blk, 0, stream>>>(XB, f1, n1_a, P, PS1, 256, 4);
  // ll1 + w1 aug: KS=4 (5-7 chunks/slice) -> 1024 blocks
  mfma_gemm<<<dim3(4, 8, 32), blk, 0, stream>>>(XB, P, WLL1, nullptr, WG1,
      f1, nullptr, 256, 512, 1, PS1, PS2, 2, 2);
  bias_silu_p<<<PS2 / 256, blk, 0, stream>>>(f1, ll1_b, act_a, act_b, HB, PS2, 512, 4);

  // ---- channel-wise GP layer: lrg + llg fused, KS=2 -> 1024 blocks ----
  mfma_gemm<<<dim3(4, 8, 32), blk, 0, stream>>>(HB, nullptr, WLRG, WLLG, nullptr,
      hrP, llgP, 512, 512, 0, PS2, PS2, 1, 3);
  cw_silu_p<<<PS2 / 256, blk, 0, stream>>>(llgP, HB, hrP, ng_a, wg, llg_b, act_a, act_b,
      HB, PS2, 512, 2);

  // ---- fcgp2 (N=512, M=128) ----
  // lr2: KS=2 (4 chunks/slice) -> 512 blocks
  mfma_gemm<<<dim3(4, 8, 16), blk, 0, stream>>>(HB, nullptr, WLR2, nullptr, nullptr,
      f1, nullptr, 512, 512, 0, PS2, PS2, 1, 3);
  pair_norm_p<<<PS2 / 256, blk, 0, stream>>>(HB, f1, n2_a, P, PS2, 512, 2);
  // ll2 + w2 aug: KS=8 (5-7 chunks/slice) -> 512 blocks
  mfma_gemm<<<dim3(1, 8, 64), blk, 0, stream>>>(HB, P, WLL2, nullptr, WG2,
      f1, nullptr, 512, 128, 1, PS2, PSO, 3, 3);
  final_p<<<PSO / 256, blk, 0, stream>>>(f1, ll2_b, out, PSO, 128, 8);
}

// Round 5
// 261.820 us; speedup vs baseline: 1.1303x; 1.1303x over previous
//
#include <hip/hip_runtime.h>
#include <math.h>

// ============================================================================
// CliffordFourierHead — Cl(3,0) CGENN block. Round 5: round-3 split-K config
// (best known) + global_load_lds width-16 DMA staging with the XOR bank
// swizzle folded into the global source address (LDS image identical to the
// old swizzled layout; MFMA loop unchanged).
// ============================================================================

typedef unsigned short u16;
typedef __attribute__((ext_vector_type(8))) short short8;
typedef __attribute__((ext_vector_type(4))) float f32x4;

#define RSQRT2F 0.70710678118654752440f

__device__ inline void gl_lds16(const void* g, void* l) {
  __builtin_amdgcn_global_load_lds(
      (const __attribute__((address_space(1))) void*)g,
      (__attribute__((address_space(3))) void*)l, 16, 0, 0);
}

// ---- Clifford product tables (verified rounds 0-4) ----
__device__ constexpr int PP_I[64] = {
  0,0,0,0,0,0,0,0,  1,1,1,1,1,1,1,1,  2,2,2,2,2,2,2,2,  3,3,3,3,3,3,3,3,
  4,4,4,4,4,4,4,4,  5,5,5,5,5,5,5,5,  6,6,6,6,6,6,6,6,  7,7,7,7,7,7,7,7};
__device__ constexpr int PP_K[64] = {
  0,1,2,3,4,5,6,7,  0,1,2,3,4,5,6,7,  0,1,2,3,4,5,6,7,  0,1,2,3,4,5,6,7,
  0,1,2,3,4,5,6,7,  0,1,2,3,4,5,6,7,  0,1,2,3,4,5,6,7,  0,1,2,3,4,5,6,7};
__device__ constexpr int PP_C[64] = {
   0, 1, 2, 3, 4, 5, 6, 7,
   9, 8,15,16,13,14,21,20,
  10,15, 8,17,12,21,14,19,
  11,16,17, 8,21,12,13,18,
  29,24,23,35,22,34,33,28,
  30,25,35,23,34,22,32,27,
  31,35,25,24,33,32,22,26,
  43,42,41,40,39,38,37,36};
__device__ constexpr int PP_T[64] = {
   0, 1, 1, 1, 2, 2, 2, 3,
   5, 4, 7, 7, 6, 6, 9, 8,
   5, 7, 4, 7, 6, 9, 6, 8,
   5, 7, 7, 4, 9, 6, 6, 8,
  13,11,11,15,10,14,14,12,
  13,11,15,11,14,10,14,12,
  13,15,11,11,14,14,10,12,
  19,18,18,18,17,17,17,16};
__device__ constexpr int PP_J[64] = {
  0,1,2,3,4,5,6,7,
  1,0,4,5,2,3,7,6,
  2,4,0,6,1,7,3,5,
  3,5,6,0,7,1,2,4,
  4,2,1,7,0,6,5,3,
  5,3,7,1,6,0,4,2,
  6,7,3,2,5,4,0,1,
  7,6,5,4,3,2,1,0};
__device__ constexpr float PP_S[64] = {
  1, 1, 1, 1, 1, 1, 1, 1,
  1, 1, 1, 1, 1, 1, 1, 1,
  1,-1, 1, 1,-1,-1, 1,-1,
  1,-1,-1, 1, 1,-1,-1, 1,
  1,-1, 1, 1,-1,-1, 1,-1,
  1,-1,-1, 1, 1,-1,-1, 1,
  1, 1,-1, 1,-1, 1,-1,-1,
  1, 1,-1, 1,-1, 1,-1,-1};

__device__ constexpr int GJ_CNT[8] = {4,6,6,6,6,6,6,4};
__device__ constexpr int GJ_C[8][6] = {
  {0,8,22,36,0,0},
  {1,9,12,23,26,37},
  {2,10,13,24,27,38},
  {3,11,14,25,28,39},
  {4,15,18,29,32,40},
  {5,16,19,30,33,41},
  {6,17,20,31,34,42},
  {7,21,35,43,0,0}};
__device__ constexpr int GJ_T[8][6] = {
  {0,4,10,16,0,0},
  {1,5,6,11,12,17},
  {1,5,6,11,12,17},
  {1,5,6,11,12,17},
  {2,7,8,13,14,18},
  {2,7,8,13,14,18},
  {2,7,8,13,14,18},
  {3,9,15,19,0,0}};
__device__ constexpr int GRADE[8] = {0,1,1,1,2,2,2,3};

__device__ inline float sigm(float x) { return 1.0f / (1.0f + expf(-x)); }
__device__ inline u16 f2bf(float f) {
  unsigned u = __float_as_uint(f);
  return (u16)((u + 0x7fffu + ((u >> 16) & 1u)) >> 16);
}
__device__ inline float bf2f(u16 h) { return __uint_as_float(((unsigned)h) << 16); }

// ============================================================================
// bf16 MFMA GEMM, multi-pass + split-K over flattened (pass, k-chunk) list.
// blockIdx.z = (set, j, slice). Slices write disjoint fp32 partial planes
// [slice*8+j][planeO]; consumers sum slices. 128x128 tile, BK=64, 4 waves,
// 4x4 frags of 16x16x32 bf16 MFMA.
// Staging: global_load_lds dwordx4; swizzle applied on the GLOBAL side so the
// LDS image has granule slot s of row r holding global granule s^(r&7); frag
// reads use slot kq^(row&7) -> conflict-free (2-way only), same as rounds 2-4.
// ============================================================================
#define BT 128
#define MT 128
#define BKc 64

__global__ __launch_bounds__(256) void mfma_gemm(
    const u16* __restrict__ Alin, const u16* __restrict__ Pfeat,
    const u16* __restrict__ WLin, const u16* __restrict__ WLin2,
    const u16* __restrict__ WGp,
    float* __restrict__ out1, float* __restrict__ out2,
    int N, int M, int aug, int planeA, int planeO, int KSbits, int KCbits)
{
  const int zz    = blockIdx.z;
  const int set   = zz >> (3 + KSbits);
  const int rem   = zz & ((8 << KSbits) - 1);
  const int j     = rem >> KSbits;
  const int slice = rem & ((1 << KSbits) - 1);
  const u16* WL   = set ? WLin2 : WLin;
  float* outp     = set ? out2 : out1;

  const int b0   = blockIdx.y * BT;
  const int m0   = blockIdx.x * MT;
  const int tid  = threadIdx.x;
  const int lane = tid & 63;
  const int wave = tid >> 6;
  const int wr   = wave >> 1;
  const int wc   = wave & 1;
  const int l15  = lane & 15;
  const int lq   = lane >> 4;

  __shared__ u16 As[BT * BKc];
  __shared__ u16 Bs[MT * BKc];

  f32x4 zero = {0.f, 0.f, 0.f, 0.f};
  f32x4 acc[4][4];
  #pragma unroll
  for (int r = 0; r < 4; ++r)
    #pragma unroll
    for (int c = 0; c < 4; ++c) acc[r][c] = zero;

  const int g = GRADE[j];
  const int npass = aug ? (1 + GJ_CNT[j]) : 1;
  const int KC = 1 << KCbits;
  const int cper = (npass << KCbits) >> KSbits;   // even division by design
  const int cbeg = slice * cper;

  // DMA staging geometry: instruction `inst` covers rows 8*inst..8*inst+7 of
  // the tile; lane covers (row = inst*8 + lane>>3, granule slot = lane&7).
  // Source granule index is slot^(row&7)  (swizzle on the global side).
  const int srow = lane >> 3;            // 0..7 within instruction
  const int sslot = lane & 7;            // LDS granule slot

  for (int ci = cbeg; ci < cbeg + cper; ++ci) {
    const int p  = ci >> KCbits;
    const int k0 = (ci & (KC - 1)) << 6;
    const u16* Abase = (p == 0) ? Alin + (size_t)j * planeA
                                : Pfeat + (size_t)GJ_C[j][p - 1] * planeA;
    const u16* Wbase = (p == 0) ? WL + (size_t)g * M * N
                                : WGp + (size_t)GJ_T[j][p - 1] * M * N;
    const u16* Asrc = Abase + (size_t)b0 * N + k0;
    const u16* Bsrc = Wbase + (size_t)m0 * N + k0;

    __syncthreads();
    #pragma unroll
    for (int q = 0; q < 4; ++q) {
      int inst = wave * 4 + q;           // 0..15, wave-uniform
      int row  = inst * 8 + srow;
      int kg   = sslot ^ (row & 7);
      gl_lds16(Asrc + (size_t)row * N + kg * 8, &As[inst * 512]);
    }
    #pragma unroll
    for (int q = 0; q < 4; ++q) {
      int inst = wave * 4 + q;
      int row  = inst * 8 + srow;
      int kg   = sslot ^ (row & 7);
      gl_lds16(Bsrc + (size_t)row * N + kg * 8, &Bs[inst * 512]);
    }
    __syncthreads();

    #pragma unroll
    for (int s = 0; s < 2; ++s) {
      const int kq = s * 4 + lq;
      short8 af[4], bfr[4];
      #pragma unroll
      for (int r = 0; r < 4; ++r) {
        int row = wr * 64 + r * 16 + l15;
        af[r] = *(const short8*)(&As[row * BKc + (kq ^ (row & 7)) * 8]);
      }
      #pragma unroll
      for (int c = 0; c < 4; ++c) {
        int row = wc * 64 + c * 16 + l15;
        bfr[c] = *(const short8*)(&Bs[row * BKc + (kq ^ (row & 7)) * 8]);
      }
      #pragma unroll
      for (int r = 0; r < 4; ++r)
        #pragma unroll
        for (int c = 0; c < 4; ++c)
          acc[r][c] = __builtin_amdgcn_mfma_f32_16x16x32_bf16(af[r], bfr[c], acc[r][c], 0, 0, 0);
    }
  }

  float* obase = outp + (size_t)(slice * 8 + j) * planeO;
  #pragma unroll
  for (int r = 0; r < 4; ++r)
    #pragma unroll
    for (int c = 0; c < 4; ++c)
      #pragma unroll
      for (int e = 0; e < 4; ++e) {
        int bb = b0 + wr * 64 + r * 16 + lq * 4 + e;
        int mm = m0 + wc * 64 + c * 16 + l15;
        obase[(size_t)bb * M + mm] = acc[r][c][e];
      }
}

// ============================================================================
// Fused repack (8 weight tensors) + xcast (y==8): fp32 -> bf16 planes
// ============================================================================
struct RepackDesc { const float* in; u16* out; int MN; int S; };
struct RepackArgs { RepackDesc d[8]; const float* x; u16* xp; int PS; };

__global__ void repack_all(RepackArgs a)
{
  int mn = blockIdx.x * 256 + threadIdx.x;
  if (blockIdx.y == 8) {
    if (mn >= a.PS) return;
    float v[8];
    *(float4*)(v)     = *(const float4*)(a.x + (size_t)mn * 8);
    *(float4*)(v + 4) = *(const float4*)(a.x + (size_t)mn * 8 + 4);
    #pragma unroll
    for (int jj = 0; jj < 8; ++jj) a.xp[(size_t)jj * a.PS + mn] = f2bf(v[jj]);
    return;
  }
  RepackDesc d = a.d[blockIdx.y];
  if (mn >= d.MN) return;
  if (d.S == 4) {
    float4 v = ((const float4*)d.in)[mn];
    d.out[(size_t)0 * d.MN + mn] = f2bf(v.x);
    d.out[(size_t)1 * d.MN + mn] = f2bf(v.y);
    d.out[(size_t)2 * d.MN + mn] = f2bf(v.z);
    d.out[(size_t)3 * d.MN + mn] = f2bf(v.w);
  } else {  // S == 20
    #pragma unroll
    for (int q = 0; q < 5; ++q) {
      float4 v = *(const float4*)(d.in + (size_t)mn * 20 + q * 4);
      d.out[(size_t)(q * 4 + 0) * d.MN + mn] = f2bf(v.x);
      d.out[(size_t)(q * 4 + 1) * d.MN + mn] = f2bf(v.y);
      d.out[(size_t)(q * 4 + 2) * d.MN + mn] = f2bf(v.z);
      d.out[(size_t)(q * 4 + 3) * d.MN + mn] = f2bf(v.w);
    }
  }
}

// fused: v = sum_slices(vpart) -> CGENN norm(na) -> pair products with u -> P bf16
__global__ void pair_norm_p(const u16* __restrict__ up, const float* __restrict__ vpart,
                            const float* __restrict__ na, u16* __restrict__ Pp,
                            int PS, int M, int KS)
{
  int t = blockIdx.x * 256 + threadIdx.x;
  if (t >= PS) return;
  int m = t % M;
  float u[8], v[8];
  #pragma unroll
  for (int jj = 0; jj < 8; ++jj) {
    u[jj] = bf2f(up[(size_t)jj * PS + t]);
    float s = 0.f;
    for (int sl = 0; sl < KS; ++sl) s += vpart[(size_t)(sl * 8 + jj) * PS + t];
    v[jj] = s;
  }
  float q[4];
  q[0] = sqrtf(v[0] * v[0]);
  q[1] = sqrtf(v[1] * v[1] + v[2] * v[2] + v[3] * v[3]);
  q[2] = sqrtf(v[4] * v[4] + v[5] * v[5] + v[6] * v[6]);
  q[3] = sqrtf(v[7] * v[7]);
  float sc[4];
  #pragma unroll
  for (int gg = 0; gg < 4; ++gg) {
    float sa = sigm(na[m * 4 + gg]);
    sc[gg] = 1.0f / (sa * (q[gg] - 1.0f) + 1.0f + 1e-6f);
  }
  #pragma unroll
  for (int jj = 0; jj < 8; ++jj) v[jj] *= sc[GRADE[jj]];
  float p[44];
  #pragma unroll
  for (int c = 0; c < 44; ++c) p[c] = 0.f;
  #pragma unroll
  for (int e = 0; e < 64; ++e)
    p[PP_C[e]] += PP_S[e] * u[PP_I[e]] * v[PP_K[e]];
  #pragma unroll
  for (int c = 0; c < 44; ++c) Pp[(size_t)c * PS + t] = f2bf(p[c]);
}

// h = mv_silu((sum_slices + bias0)/sqrt2) -> bf16 planes
__global__ void bias_silu_p(const float* __restrict__ hpart, const float* __restrict__ bias,
                            const float* __restrict__ ga, const float* __restrict__ gb,
                            u16* __restrict__ sh, int PS, int M, int KS)
{
  int t = blockIdx.x * 256 + threadIdx.x;
  if (t >= PS) return;
  int m = t % M;
  float v[8];
  #pragma unroll
  for (int jj = 0; jj < 8; ++jj) {
    float s = 0.f;
    for (int sl = 0; sl < KS; ++sl) s += hpart[(size_t)(sl * 8 + jj) * PS + t];
    v[jj] = s;
  }
  v[0] += bias[m];
  #pragma unroll
  for (int jj = 0; jj < 8; ++jj) v[jj] *= RSQRT2F;
  float inv[4];
  inv[0] = v[0];
  inv[1] = v[1]*v[1] + v[2]*v[2] + v[3]*v[3];
  inv[2] = v[4]*v[4] + v[5]*v[5] + v[6]*v[6];
  inv[3] = v[7]*v[7];
  float gt[4];
  #pragma unroll
  for (int gg = 0; gg < 4; ++gg)
    gt[gg] = sigm(ga[m * 4 + gg] * inv[gg] + gb[m * 4 + gg]);
  #pragma unroll
  for (int jj = 0; jj < 8; ++jj)
    sh[(size_t)jj * PS + t] = f2bf(v[jj] * gt[GRADE[jj]]);
}

// h2 = mv_silu((llg + bias0 + cwGP(u, norm(hr); wg))/sqrt2) -> bf16 planes
__global__ void cw_silu_p(const float* __restrict__ llg, const u16* __restrict__ up,
                          const float* __restrict__ hrraw, const float* __restrict__ na,
                          const float* __restrict__ wg, const float* __restrict__ bias,
                          const float* __restrict__ ga, const float* __restrict__ gb,
                          u16* __restrict__ sh, int PS, int M)
{
  int t = blockIdx.x * 256 + threadIdx.x;
  if (t >= PS) return;
  int n = t % M;
  float acc[8], u[8], v[8], w[20];
  #pragma unroll
  for (int jj = 0; jj < 8; ++jj) {
    acc[jj] = llg[(size_t)jj * PS + t];
    u[jj]   = bf2f(up[(size_t)jj * PS + t]);
    v[jj]   = hrraw[(size_t)jj * PS + t];
  }
  float q[4];
  q[0] = sqrtf(v[0] * v[0]);
  q[1] = sqrtf(v[1] * v[1] + v[2] * v[2] + v[3] * v[3]);
  q[2] = sqrtf(v[4] * v[4] + v[5] * v[5] + v[6] * v[6]);
  q[3] = sqrtf(v[7] * v[7]);
  float sc[4];
  #pragma unroll
  for (int gg = 0; gg < 4; ++gg) {
    float sa = sigm(na[n * 4 + gg]);
    sc[gg] = 1.0f / (sa * (q[gg] - 1.0f) + 1.0f + 1e-6f);
  }
  #pragma unroll
  for (int jj = 0; jj < 8; ++jj) v[jj] *= sc[GRADE[jj]];
  #pragma unroll
  for (int qq = 0; qq < 5; ++qq)
    *(float4*)(w + qq * 4) = *(const float4*)(wg + (size_t)n * 20 + qq * 4);
  acc[0] += bias[n];
  #pragma unroll
  for (int e = 0; e < 64; ++e)
    acc[PP_J[e]] += PP_S[e] * u[PP_I[e]] * v[PP_K[e]] * w[PP_T[e]];
  #pragma unroll
  for (int jj = 0; jj < 8; ++jj) acc[jj] *= RSQRT2F;
  float inv[4];
  inv[0] = acc[0];
  inv[1] = acc[1]*acc[1] + acc[2]*acc[2] + acc[3]*acc[3];
  inv[2] = acc[4]*acc[4] + acc[5]*acc[5] + acc[6]*acc[6];
  inv[3] = acc[7]*acc[7];
  float gt[4];
  #pragma unroll
  for (int gg = 0; gg < 4; ++gg)
    gt[gg] = sigm(ga[n * 4 + gg] * inv[gg] + gb[n * 4 + gg]);
  #pragma unroll
  for (int jj = 0; jj < 8; ++jj)
    sh[(size_t)jj * PS + t] = f2bf(acc[jj] * gt[GRADE[jj]]);
}

// out[b,m,j] = (sum_slices + bias0)/sqrt2, planar -> interleaved
__global__ void final_p(const float* __restrict__ pre, const float* __restrict__ bias,
                        float* __restrict__ outp, int PS, int M, int KS)
{
  int t = blockIdx.x * 256 + threadIdx.x;
  if (t >= PS) return;
  int m = t % M;
  float v[8];
  #pragma unroll
  for (int jj = 0; jj < 8; ++jj) {
    float s = 0.f;
    for (int sl = 0; sl < KS; ++sl) s += pre[(size_t)(sl * 8 + jj) * PS + t];
    v[jj] = s;
  }
  v[0] += bias[m];
  #pragma unroll
  for (int jj = 0; jj < 8; ++jj) v[jj] *= RSQRT2F;
  *(float4*)(outp + (size_t)t * 8)     = *(float4*)(v);
  *(float4*)(outp + (size_t)t * 8 + 4) = *(float4*)(v + 4);
}

// ============================================================================
extern "C" void kernel_launch(void* const* d_in, const int* in_sizes, int n_in,
                              void* d_out, int out_size, void* d_ws, size_t ws_size,
                              hipStream_t stream)
{
  const float* x     = (const float*)d_in[0];
  const float* lr1_w = (const float*)d_in[1];
  const float* n1_a  = (const float*)d_in[2];
  const float* ll1_w = (const float*)d_in[3];
  const float* ll1_b = (const float*)d_in[4];
  const float* w1    = (const float*)d_in[5];
  const float* act_a = (const float*)d_in[6];
  const float* act_b = (const float*)d_in[7];
  const float* lrg_w = (const float*)d_in[8];
  const float* ng_a  = (const float*)d_in[9];
  const float* llg_w = (const float*)d_in[10];
  const float* llg_b = (const float*)d_in[11];
  const float* wg    = (const float*)d_in[12];
  const float* lr2_w = (const float*)d_in[13];
  const float* n2_a  = (const float*)d_in[14];
  const float* ll2_w = (const float*)d_in[15];
  const float* ll2_b = (const float*)d_in[16];
  const float* w2    = (const float*)d_in[17];
  float* out = (float*)d_out;

  // ---- workspace carve-up ----
  u16* W = (u16*)d_ws;
  size_t o = 0;
  u16* WL1  = W + o; o +=  262144;   // [4][256*256]
  u16* WLL1 = W + o; o +=  524288;   // [4][512*256]
  u16* WG1  = W + o; o += 2621440;   // [20][512*256]
  u16* WLRG = W + o; o += 1048576;   // [4][512*512]
  u16* WLLG = W + o; o += 1048576;
  u16* WLR2 = W + o; o += 1048576;
  u16* WLL2 = W + o; o +=  262144;   // [4][128*512]
  u16* WG2  = W + o; o += 1310720;   // [20][128*512]
  u16* XB   = W + o; o += 2097152;   // [8][1024*256]
  u16* HB   = W + o; o += 4194304;   // [8][1024*512] (h1 bf16, then h2 bf16)
  u16* P    = W + o; o += 23068672;  // [44][1024*512]
  float* f1 = (float*)(W + o);       // 8,388,608 f: lr1 part(KS2) / ll1 part(KS2) / lr2 part(KS2) / outPre part(KS8)
  float* f2 = f1 + 8388608;          // 8,388,608 f: hr(16MB)+llg(16MB), KS=1
  float* hrP  = f2;
  float* llgP = f2 + 4194304;

  dim3 blk(256);
  const int PS1 = 1024 * 256, PS2 = 1024 * 512, PSO = 1024 * 128;

  // ---- fused repacks + xcast ----
  RepackArgs ra = {{
    {lr1_w, WL1, 65536, 4}, {ll1_w, WLL1, 131072, 4}, {w1, WG1, 131072, 20},
    {lrg_w, WLRG, 262144, 4}, {llg_w, WLLG, 262144, 4}, {lr2_w, WLR2, 262144, 4},
    {ll2_w, WLL2, 65536, 4}, {w2, WG2, 65536, 20}},
    x, XB, PS1};
  repack_all<<<dim3(1024, 9), blk, 0, stream>>>(ra);

  // ---- fcgp1 (N=256, M=512) ----
  // lr1: KS=2 -> 256 blocks
  mfma_gemm<<<dim3(2, 8, 16), blk, 0, stream>>>(XB, nullptr, WL1, nullptr, nullptr,
      f1, nullptr, 256, 256, 0, PS1, PS1, 1, 2);
  pair_norm_p<<<PS1 / 256, blk, 0, stream>>>(XB, f1, n1_a, P, PS1, 256, 2);
  // ll1 + w1 aug: KS=2 -> 512 blocks
  mfma_gemm<<<dim3(4, 8, 16), blk, 0, stream>>>(XB, P, WLL1, nullptr, WG1,
      f1, nullptr, 256, 512, 1, PS1, PS2, 1, 2);
  bias_silu_p<<<PS2 / 256, blk, 0, stream>>>(f1, ll1_b, act_a, act_b, HB, PS2, 512, 2);

  // ---- channel-wise GP layer: lrg + llg fused, KS=1 -> 512 blocks ----
  mfma_gemm<<<dim3(4, 8, 16), blk, 0, stream>>>(HB, nullptr, WLRG, WLLG, nullptr,
      hrP, llgP, 512, 512, 0, PS2, PS2, 0, 3);
  cw_silu_p<<<PS2 / 256, blk, 0, stream>>>(llgP, HB, hrP, ng_a, wg, llg_b, act_a, act_b,
      HB, PS2, 512);

  // ---- fcgp2 (N=512, M=128) ----
  // lr2: KS=2 -> 512 blocks
  mfma_gemm<<<dim3(4, 8, 16), blk, 0, stream>>>(HB, nullptr, WLR2, nullptr, nullptr,
      f1, nullptr, 512, 512, 0, PS2, PS2, 1, 3);
  pair_norm_p<<<PS2 / 256, blk, 0, stream>>>(HB, f1, n2_a, P, PS2, 512, 2);
  // ll2 + w2 aug: KS=8 -> 512 blocks
  mfma_gemm<<<dim3(1, 8, 64), blk, 0, stream>>>(HB, P, WLL2, nullptr, WG2,
      f1, nullptr, 512, 128, 1, PS2, PSO, 3, 3);
  final_p<<<PSO / 256, blk, 0, stream>>>(f1, ll2_b, out, PSO, 128, 8);
}